// Round 8
// baseline (442.197 us; speedup 1.0000x reference)
//
#include <hip/hip_runtime.h>
#include <math.h>

#define EPS_OT 0.05f
#define INV_EPS 20.0f

typedef unsigned short ushort_t;
typedef __attribute__((ext_vector_type(8))) short short8;
typedef __attribute__((ext_vector_type(4))) float f32x4;
union Pk { uint4 u; short8 s; };

__device__ __forceinline__ unsigned int f2bf(float f) {  // RNE f32->bf16
  unsigned int u = __float_as_uint(f);
  return (u + 0x7FFFu + ((u >> 16) & 1u)) >> 16;
}
__device__ __forceinline__ float bf2f(unsigned int u) { return __uint_as_float(u << 16); }

// lgkmcnt-only barrier: orders LDS producer->consumer across the workgroup but
// does NOT drain vmcnt (mailbox store-ack / in-flight poll load survive it).
__device__ __forceinline__ void bar_lds() {
  asm volatile("s_waitcnt lgkmcnt(0)" ::: "memory");
  __builtin_amdgcn_s_barrier();
  asm volatile("" ::: "memory");
}

// ---------------- pack: fp32 -> hi/lo bf16 (one-time) ----------------
__global__ __launch_bounds__(256) void pack_k(const float* __restrict__ F_t,
                                              const float* __restrict__ F_s,
                                              const float* __restrict__ Wq,
                                              const float* __restrict__ Wk,
                                              const float* __restrict__ Wv,
                                              const float* __restrict__ Wp,
                                              ushort_t* __restrict__ Fth, ushort_t* __restrict__ Ftl,
                                              ushort_t* __restrict__ Fsh, ushort_t* __restrict__ Fsl,
                                              ushort_t* __restrict__ Wqh, ushort_t* __restrict__ Wql,
                                              ushort_t* __restrict__ Wkh, ushort_t* __restrict__ Wkl,
                                              ushort_t* __restrict__ Wvh, ushort_t* __restrict__ Wvl,
                                              ushort_t* __restrict__ Wph) {
  const int blk = blockIdx.x;
  const float* src; ushort_t* dh; ushort_t* dl; size_t off;
  if (blk < 2048)      { src = F_t; dh = Fth; dl = Ftl; off = (size_t)blk * 1024; }
  else if (blk < 6656) { src = F_s; dh = Fsh; dl = Fsl; off = (size_t)(blk - 2048) * 1024; }
  else if (blk < 6912) { src = Wq;  dh = Wqh; dl = Wql; off = (size_t)(blk - 6656) * 1024; }
  else if (blk < 7168) { src = Wk;  dh = Wkh; dl = Wkl; off = (size_t)(blk - 6912) * 1024; }
  else if (blk < 7424) { src = Wv;  dh = Wvh; dl = Wvl; off = (size_t)(blk - 7168) * 1024; }
  else                 { src = Wp;  dh = Wph; dl = nullptr; off = (size_t)(blk - 7424) * 1024; }
  const size_t i = off + (size_t)threadIdx.x * 4;
  float4 f = *(const float4*)(src + i);
  unsigned int h0 = f2bf(f.x), h1 = f2bf(f.y), h2 = f2bf(f.z), h3 = f2bf(f.w);
  uint2 hh; hh.x = h0 | (h1 << 16); hh.y = h2 | (h3 << 16);
  *(uint2*)(dh + i) = hh;
  if (dl) {
    uint2 ll;
    ll.x = f2bf(f.x - bf2f(h0)) | (f2bf(f.y - bf2f(h1)) << 16);
    ll.y = f2bf(f.z - bf2f(h2)) | (f2bf(f.w - bf2f(h3)) << 16);
    *(uint2*)(dl + i) = ll;
  }
}

// ====== hi/lo GEMM main loop on pre-packed bf16 (64x64 tile, K=512, 3-MFMA) ======
#define GEMM_HL_BODY()                                                                      \
  f32x4 acc[4] = {};                                                                        \
  for (int k0 = 0; k0 < 512; k0 += 64) {                                                    \
    uint4 a0 = *(const uint4*)(Xp_h + k0), a1 = *(const uint4*)(Xp_h + k0 + 8);             \
    uint4 b0 = *(const uint4*)(Xp_l + k0), b1 = *(const uint4*)(Xp_l + k0 + 8);             \
    uint4 c0 = *(const uint4*)(Wp_h + k0), c1 = *(const uint4*)(Wp_h + k0 + 8);             \
    uint4 d0 = *(const uint4*)(Wp_l + k0), d1 = *(const uint4*)(Wp_l + k0 + 8);             \
    __syncthreads();                                                                        \
    *(uint4*)&Xh[r][cg * 16] = a0; *(uint4*)&Xh[r][cg * 16 + 8] = a1;                       \
    *(uint4*)&Xl[r][cg * 16] = b0; *(uint4*)&Xl[r][cg * 16 + 8] = b1;                       \
    *(uint4*)&Wh[r][cg * 16] = c0; *(uint4*)&Wh[r][cg * 16 + 8] = c1;                       \
    *(uint4*)&Wl[r][cg * 16] = d0; *(uint4*)&Wl[r][cg * 16 + 8] = d1;                       \
    __syncthreads();                                                                        \
    _Pragma("unroll") for (int kst = 0; kst < 2; ++kst) {                                   \
      short8 ah = *(const short8*)&Xh[16 * w + li][kst * 32 + 8 * lg];                      \
      short8 al = *(const short8*)&Xl[16 * w + li][kst * 32 + 8 * lg];                      \
      _Pragma("unroll") for (int nt = 0; nt < 4; ++nt) {                                    \
        short8 bh = *(const short8*)&Wh[nt * 16 + li][kst * 32 + 8 * lg];                   \
        short8 bl = *(const short8*)&Wl[nt * 16 + li][kst * 32 + 8 * lg];                   \
        acc[nt] = __builtin_amdgcn_mfma_f32_16x16x32_bf16(ah, bh, acc[nt], 0, 0, 0);        \
        acc[nt] = __builtin_amdgcn_mfma_f32_16x16x32_bf16(ah, bl, acc[nt], 0, 0, 0);        \
        acc[nt] = __builtin_amdgcn_mfma_f32_16x16x32_bf16(al, bh, acc[nt], 0, 0, 0);        \
      }                                                                                     \
    }                                                                                       \
  }

// ====== plain bf16 GEMM main loop (64x64 tile, K=512, 1-MFMA) ======
#define GEMM_PL_BODY()                                                                      \
  f32x4 acc[4] = {};                                                                        \
  for (int k0 = 0; k0 < 512; k0 += 64) {                                                    \
    uint4 a0 = *(const uint4*)(Xp_h + k0), a1 = *(const uint4*)(Xp_h + k0 + 8);             \
    uint4 c0 = *(const uint4*)(Wp_h + k0), c1 = *(const uint4*)(Wp_h + k0 + 8);             \
    __syncthreads();                                                                        \
    *(uint4*)&Xh[r][cg * 16] = a0; *(uint4*)&Xh[r][cg * 16 + 8] = a1;                       \
    *(uint4*)&Wh[r][cg * 16] = c0; *(uint4*)&Wh[r][cg * 16 + 8] = c1;                       \
    __syncthreads();                                                                        \
    _Pragma("unroll") for (int kst = 0; kst < 2; ++kst) {                                   \
      short8 ah = *(const short8*)&Xh[16 * w + li][kst * 32 + 8 * lg];                      \
      _Pragma("unroll") for (int nt = 0; nt < 4; ++nt) {                                    \
        short8 bh = *(const short8*)&Wh[nt * 16 + li][kst * 32 + 8 * lg];                   \
        acc[nt] = __builtin_amdgcn_mfma_f32_16x16x32_bf16(ah, bh, acc[nt], 0, 0, 0);        \
      }                                                                                     \
    }                                                                                       \
  }

// ------- fused GEMM + per-head l2norm -> hi/lo bf16 [B*H][Nn][64] (q and k) -------
__global__ __launch_bounds__(256) void gemmnorm2_k(const ushort_t* __restrict__ Xg_h,
                                                   const ushort_t* __restrict__ Xg_l,
                                                   const ushort_t* __restrict__ Wg_h,
                                                   const ushort_t* __restrict__ Wg_l,
                                                   const float* __restrict__ bias,
                                                   ushort_t* __restrict__ oh,
                                                   ushort_t* __restrict__ ol, int Nn) {
  __shared__ ushort_t Xh[64][72], Xl[64][72], Wh[64][72], Wl[64][72];
  const int tid = threadIdx.x;
  const int w = tid >> 6, l = tid & 63, li = l & 15, lg = l >> 4;
  const int r = tid >> 2, cg = tid & 3;
  const int m0 = blockIdx.x << 6;
  const int h = blockIdx.y, n0 = h << 6;
  const ushort_t* Xp_h = Xg_h + (size_t)(m0 + r) * 512 + cg * 16;
  const ushort_t* Xp_l = Xg_l + (size_t)(m0 + r) * 512 + cg * 16;
  const ushort_t* Wp_h = Wg_h + (size_t)(n0 + r) * 512 + cg * 16;
  const ushort_t* Wp_l = Wg_l + (size_t)(n0 + r) * 512 + cg * 16;
  GEMM_HL_BODY()
  float v[4][4];
  float ss[4] = {0.f, 0.f, 0.f, 0.f};
#pragma unroll
  for (int nt = 0; nt < 4; ++nt) {
    float bb = bias[n0 + nt * 16 + li];
#pragma unroll
    for (int reg = 0; reg < 4; ++reg) {
      float y = acc[nt][reg] + bb;
      v[nt][reg] = y;
      ss[reg] = fmaf(y, y, ss[reg]);
    }
  }
#pragma unroll
  for (int off = 1; off < 16; off <<= 1)
#pragma unroll
    for (int reg = 0; reg < 4; ++reg) ss[reg] += __shfl_xor(ss[reg], off, 64);
  const int b = m0 / Nn;
  const int nbase = m0 - b * Nn;
  const size_t base = ((size_t)(b * 8 + h) * Nn + nbase + 16 * w + 4 * lg) * 64;
#pragma unroll
  for (int reg = 0; reg < 4; ++reg) {
    float inv = 1.0f / fmaxf(sqrtf(ss[reg]), 1e-12f);
#pragma unroll
    for (int nt = 0; nt < 4; ++nt) {
      float y = v[nt][reg] * inv;
      unsigned int hi = f2bf(y);
      size_t idx = base + (size_t)reg * 64 + nt * 16 + li;
      oh[idx] = (ushort_t)hi;
      ol[idx] = (ushort_t)f2bf(y - bf2f(hi));
    }
  }
}

// ------- fused plain-bf16 GEMM + transpose: vt[s][c 0..63][j 0..575] (v path) -------
__global__ __launch_bounds__(256) void gemmtrans2_k(const ushort_t* __restrict__ Xg_h,
                                                    const ushort_t* __restrict__ Wg_h,
                                                    const float* __restrict__ bias,
                                                    ushort_t* __restrict__ vt) {
  __shared__ ushort_t Xh[64][72], Wh[64][72];
  __shared__ ushort_t Vs[64 * 73];
  const int tid = threadIdx.x;
  const int w = tid >> 6, l = tid & 63, li = l & 15, lg = l >> 4;
  const int r = tid >> 2, cg = tid & 3;
  const int m0 = blockIdx.x << 6;
  const int h = blockIdx.y, n0 = h << 6;
  const ushort_t* Xp_h = Xg_h + (size_t)(m0 + r) * 512 + cg * 16;
  const ushort_t* Wp_h = Wg_h + (size_t)(n0 + r) * 512 + cg * 16;
  GEMM_PL_BODY()
#pragma unroll
  for (int nt = 0; nt < 4; ++nt) {
    float bb = bias[n0 + nt * 16 + li];
#pragma unroll
    for (int reg = 0; reg < 4; ++reg)
      Vs[(16 * w + 4 * lg + reg) * 73 + nt * 16 + li] = (ushort_t)f2bf(acc[nt][reg] + bb);
  }
  __syncthreads();
  const int a9 = m0 >> 6;
  const int b = a9 / 9;
  const int nbase = m0 - b * 576;
  const int s = b * 8 + h;
  const int c = tid >> 2, q4 = tid & 3;
  ushort_t tmp[16];
#pragma unroll
  for (int jj = 0; jj < 16; ++jj) tmp[jj] = Vs[(q4 * 16 + jj) * 73 + c];
  ushort_t* op = vt + ((size_t)s * 64 + c) * 576 + nbase + q4 * 16;
  *(uint4*)op = *(uint4*)&tmp[0];
  *(uint4*)(op + 8) = *(uint4*)&tmp[8];
}

// ------- final plain-bf16 GEMM (scorev-out bf16 @ Wp_h) -> fp32 -------
__global__ __launch_bounds__(256) void gemmplain_k(const ushort_t* __restrict__ Xg_h,
                                                   const ushort_t* __restrict__ Wg_h,
                                                   const float* __restrict__ bias,
                                                   float* __restrict__ Y) {
  __shared__ ushort_t Xh[64][72], Wh[64][72];
  const int tid = threadIdx.x;
  const int w = tid >> 6, l = tid & 63, li = l & 15, lg = l >> 4;
  const int r = tid >> 2, cg = tid & 3;
  const int m0 = blockIdx.x << 6, n0 = blockIdx.y << 6;
  const ushort_t* Xp_h = Xg_h + (size_t)(m0 + r) * 512 + cg * 16;
  const ushort_t* Wp_h = Wg_h + (size_t)(n0 + r) * 512 + cg * 16;
  GEMM_PL_BODY()
#pragma unroll
  for (int nt = 0; nt < 4; ++nt) {
    float bb = bias[n0 + nt * 16 + li];
#pragma unroll
    for (int reg = 0; reg < 4; ++reg)
      Y[(size_t)(m0 + 16 * w + 4 * lg + reg) * 512 + n0 + nt * 16 + li] = acc[nt][reg] + bb;
  }
}

// ---------- simE: E[s][i][j] = bf16(exp((q.k - 1)*20)), MFMA hi/lo ----------
__global__ __launch_bounds__(256) void simE2_k(const ushort_t* __restrict__ qh,
                                               const ushort_t* __restrict__ ql,
                                               const ushort_t* __restrict__ kh,
                                               const ushort_t* __restrict__ kl,
                                               ushort_t* __restrict__ E) {
  const int s = blockIdx.x, i0 = blockIdx.y << 6, j0 = blockIdx.z << 6;
  const int tid = threadIdx.x;
  const int w = tid >> 6, l = tid & 63, li = l & 15, lg = l >> 4;
  const size_t qoff = ((size_t)s * 256 + i0 + 16 * w + li) * 64 + 8 * lg;
  short8 aH0 = *(const short8*)(qh + qoff), aH1 = *(const short8*)(qh + qoff + 32);
  short8 aL0 = *(const short8*)(ql + qoff), aL1 = *(const short8*)(ql + qoff + 32);
  f32x4 acc[4] = {};
#pragma unroll
  for (int nt = 0; nt < 4; ++nt) {
    const size_t koff = ((size_t)s * 576 + j0 + nt * 16 + li) * 64 + 8 * lg;
    short8 bH0 = *(const short8*)(kh + koff), bH1 = *(const short8*)(kh + koff + 32);
    short8 bL0 = *(const short8*)(kl + koff), bL1 = *(const short8*)(kl + koff + 32);
    acc[nt] = __builtin_amdgcn_mfma_f32_16x16x32_bf16(aH0, bH0, acc[nt], 0, 0, 0);
    acc[nt] = __builtin_amdgcn_mfma_f32_16x16x32_bf16(aH1, bH1, acc[nt], 0, 0, 0);
    acc[nt] = __builtin_amdgcn_mfma_f32_16x16x32_bf16(aH0, bL0, acc[nt], 0, 0, 0);
    acc[nt] = __builtin_amdgcn_mfma_f32_16x16x32_bf16(aH1, bL1, acc[nt], 0, 0, 0);
    acc[nt] = __builtin_amdgcn_mfma_f32_16x16x32_bf16(aL0, bH0, acc[nt], 0, 0, 0);
    acc[nt] = __builtin_amdgcn_mfma_f32_16x16x32_bf16(aL1, bH1, acc[nt], 0, 0, 0);
  }
  ushort_t* Ep = E + (size_t)s * 147456;
#pragma unroll
  for (int nt = 0; nt < 4; ++nt)
#pragma unroll
    for (int reg = 0; reg < 4; ++reg) {
      float e = __expf((acc[nt][reg] - 1.0f) * INV_EPS);
      Ep[(size_t)(i0 + 16 * w + 4 * lg + reg) * 576 + j0 + nt * 16 + li] = (ushort_t)f2bf(e);
    }
}

// -------- Sinkhorn v16: 1 barrier/iter, all-register role-split --------
// Row waves 0-7: row-tile w x 18 chunks (3 interleaved 6-chains) -> full rowsum
//   in-lane -> u-update in-wave (no rpart, no uu). u kept in register.
// Col waves 8-15: 4-5 col-tiles (frag[16] + 1 LDS-stashed tile for wc<4) ->
//   colsum in-register -> publish -> BATCH poll own tiles' partner cols
//   (pipelined loads + joint spin; fixes v13's serial-spin poison) ->
//   v-update in-wave (no cso, no vv). v kept in registers.
// mv1 reads bv written LAST iter (ping-pong); both per-iter chains independent
// -> ONE bar_lds()/iter. Mailbox protocol identical to v12 (2-deep parity).
// Numerics: colsum chains bit-identical to v15; rowsum 3x6 reassoc ~1e-7.
#define SK_SMEM 147456

__global__ __launch_bounds__(1024, 1) void sinkhorn16_k(const ushort_t* __restrict__ E,
                                                        float* __restrict__ gA,
                                                        float* __restrict__ gB,
                                                        unsigned long long* __restrict__ gpart,
                                                        float C_mu, float C_nu) {
  extern __shared__ char smem[];
  const int g = blockIdx.x, s = g >> 1, rh = g & 1, pg = g ^ 1;
  const int tid = threadIdx.x, w = tid >> 6, l = tid & 63, li = l & 15, lg = l >> 4;
  unsigned long long* myP = gpart + (size_t)g * 1152;
  const unsigned long long* prP = gpart + (size_t)pg * 1152;

  ushort_t* Elds = (ushort_t*)smem;  // [128][576]
  {
    const uint4* Eg = (const uint4*)(E + (size_t)s * 147456 + (size_t)rh * 73728);
    uint4* El4 = (uint4*)Elds;
    for (int idx = tid; idx < 9216; idx += 1024) El4[idx] = Eg[idx];
  }
  __syncthreads();

  const int wc = w - 8;
  short8 frag[18];
  short8 sfr0, sfr1, sfr2, sfr3;  // 5th-tile temps (col waves wc<4)
#define BFRV(dst, tc, q)                                                       \
  {                                                                            \
    const ushort_t* p = Elds + ((q) * 32 + 8 * lg) * 576 + (tc) * 16 + li;     \
    Pk pk;                                                                     \
    pk.u.x = (unsigned int)p[0]    | ((unsigned int)p[576]  << 16);            \
    pk.u.y = (unsigned int)p[1152] | ((unsigned int)p[1728] << 16);            \
    pk.u.z = (unsigned int)p[2304] | ((unsigned int)p[2880] << 16);            \
    pk.u.w = (unsigned int)p[3456] | ((unsigned int)p[4032] << 16);            \
    dst = pk.s;                                                                \
  }
  if (w < 8) {
    const int art = w * 16 + li;
#pragma unroll
    for (int c = 0; c < 18; ++c)
      frag[c] = *(const short8*)(Elds + art * 576 + c * 32 + 8 * lg);
    sfr0 = frag[0]; sfr1 = frag[0]; sfr2 = frag[0]; sfr3 = frag[0];
  } else {
#pragma unroll
    for (int j = 0; j < 4; ++j)
#pragma unroll
      for (int q = 0; q < 4; ++q) BFRV(frag[j * 4 + q], wc + 8 * j, q)
    frag[16] = frag[0]; frag[17] = frag[0];
    if (wc < 4) {
      BFRV(sfr0, wc + 32, 0) BFRV(sfr1, wc + 32, 1)
      BFRV(sfr2, wc + 32, 2) BFRV(sfr3, wc + 32, 3)
    } else {
      sfr0 = frag[0]; sfr1 = frag[0]; sfr2 = frag[0]; sfr3 = frag[0];
    }
  }
  __syncthreads();

  // ---- overlay scratch (Elds consumed; E lives in registers + stash) ----
  ushort_t* au = (ushort_t*)smem;        // [2][128] bf16 ping-pong
  ushort_t* bv = au + 256;               // [2][576] bf16 ping-pong
  uint4* stash = (uint4*)(bv + 1152);    // [4 waves][4 chunks][64 lanes] 16KB

  if (tid < 128) au[tid] = (ushort_t)0x3F80;
  if (tid < 576) bv[tid] = (ushort_t)0x3F80;
  if (w >= 8 && wc < 4) {
    Pk t0, t1, t2, t3;
    t0.s = sfr0; t1.s = sfr1; t2.s = sfr2; t3.s = sfr3;
    stash[(wc * 4 + 0) * 64 + l] = t0.u;
    stash[(wc * 4 + 1) * 64 + l] = t1.u;
    stash[(wc * 4 + 2) * 64 + l] = t2.u;
    stash[(wc * 4 + 3) * 64 + l] = t3.u;
  }
  __syncthreads();

  float u_r = 0.f;
  float v_r0 = 0.f, v_r1 = 0.f, v_r2 = 0.f, v_r3 = 0.f, v_r4 = 0.f;

  for (int t = 0; t < 100; ++t) {
    const int rd = t & 1, wr = rd ^ 1, par = t & 1;
    if (w < 8) {
      // ======== row path: mv1 (3 interleaved 6-chains) -> in-lane u-update ========
      const ushort_t* bvr = bv + rd * 576;
      f32x4 x1 = {0.f, 0.f, 0.f, 0.f}, y1 = {0.f, 0.f, 0.f, 0.f}, z1 = {0.f, 0.f, 0.f, 0.f};
#pragma unroll
      for (int k = 0; k < 6; ++k) {
        Pk b0, b1, b2;
        b0.u = *(const uint4*)(bvr + k * 32 + 8 * lg);
        b1.u = *(const uint4*)(bvr + (6 + k) * 32 + 8 * lg);
        b2.u = *(const uint4*)(bvr + (12 + k) * 32 + 8 * lg);
        x1 = __builtin_amdgcn_mfma_f32_16x16x32_bf16(b0.s, frag[k], x1, 0, 0, 0);
        y1 = __builtin_amdgcn_mfma_f32_16x16x32_bf16(b1.s, frag[6 + k], y1, 0, 0, 0);
        z1 = __builtin_amdgcn_mfma_f32_16x16x32_bf16(b2.s, frag[12 + k], z1, 0, 0, 0);
      }
      if (l < 16) {
        float rs = (x1[0] + y1[0]) + z1[0];
        float un = C_mu - EPS_OT * __logf(rs);
        u_r = un;
        au[wr * 128 + w * 16 + l] =
            (ushort_t)f2bf(__expf(fminf(fmaxf(un * INV_EPS, -80.f), 80.f)));
      }
    } else {
      // ======== col path: mv2 -> publish -> batch poll -> in-lane v-update ========
      const ushort_t* aur = au + rd * 128;
      Pk q0, q1, q2, q3;
      q0.u = *(const uint4*)(aur + 8 * lg);
      q1.u = *(const uint4*)(aur + 32 + 8 * lg);
      q2.u = *(const uint4*)(aur + 64 + 8 * lg);
      q3.u = *(const uint4*)(aur + 96 + 8 * lg);
      const unsigned long long tagpv = ((unsigned long long)(unsigned int)(t + 1) << 32);
      float cs0, cs1, cs2, cs3, cs4 = 0.f;
#define MV2T(CSV, F0, F1, F2, F3, TC)                                                \
      {                                                                              \
        f32x4 a2 = {0.f, 0.f, 0.f, 0.f}, b2 = {0.f, 0.f, 0.f, 0.f};                  \
        a2 = __builtin_amdgcn_mfma_f32_16x16x32_bf16(q0.s, F0, a2, 0, 0, 0);         \
        b2 = __builtin_amdgcn_mfma_f32_16x16x32_bf16(q2.s, F2, b2, 0, 0, 0);         \
        a2 = __builtin_amdgcn_mfma_f32_16x16x32_bf16(q1.s, F1, a2, 0, 0, 0);         \
        b2 = __builtin_amdgcn_mfma_f32_16x16x32_bf16(q3.s, F3, b2, 0, 0, 0);         \
        CSV = a2[0] + b2[0];                                                         \
        if (l < 16)                                                                  \
          __hip_atomic_store(&myP[par * 576 + (TC) * 16 + l],                        \
                             (unsigned long long)__float_as_uint(CSV) | tagpv,       \
                             __ATOMIC_RELAXED, __HIP_MEMORY_SCOPE_AGENT);            \
      }
      MV2T(cs0, frag[0], frag[1], frag[2], frag[3], wc + 0)
      MV2T(cs1, frag[4], frag[5], frag[6], frag[7], wc + 8)
      MV2T(cs2, frag[8], frag[9], frag[10], frag[11], wc + 16)
      MV2T(cs3, frag[12], frag[13], frag[14], frag[15], wc + 24)
      if (wc < 4) {
        Pk s0, s1, s2, s3;
        s0.u = stash[(wc * 4 + 0) * 64 + l];
        s1.u = stash[(wc * 4 + 1) * 64 + l];
        s2.u = stash[(wc * 4 + 2) * 64 + l];
        s3.u = stash[(wc * 4 + 3) * 64 + l];
        MV2T(cs4, s0.s, s1.s, s2.s, s3.s, wc + 32)
      }
      if (l < 16) {
        const unsigned int tg = (unsigned int)(t + 1);
        const unsigned long long* pb = prP + par * 576 + l;
        unsigned long long p0, p1, p2, p3, p4 = tagpv;
        p0 = __hip_atomic_load(&pb[(wc + 0) * 16], __ATOMIC_RELAXED, __HIP_MEMORY_SCOPE_AGENT);
        p1 = __hip_atomic_load(&pb[(wc + 8) * 16], __ATOMIC_RELAXED, __HIP_MEMORY_SCOPE_AGENT);
        p2 = __hip_atomic_load(&pb[(wc + 16) * 16], __ATOMIC_RELAXED, __HIP_MEMORY_SCOPE_AGENT);
        p3 = __hip_atomic_load(&pb[(wc + 24) * 16], __ATOMIC_RELAXED, __HIP_MEMORY_SCOPE_AGENT);
        if (wc < 4)
          p4 = __hip_atomic_load(&pb[(wc + 32) * 16], __ATOMIC_RELAXED, __HIP_MEMORY_SCOPE_AGENT);
        for (;;) {
          bool ok = ((unsigned int)(p0 >> 32) == tg) && ((unsigned int)(p1 >> 32) == tg) &&
                    ((unsigned int)(p2 >> 32) == tg) && ((unsigned int)(p3 >> 32) == tg) &&
                    ((unsigned int)(p4 >> 32) == tg);
          if (ok) break;
          __builtin_amdgcn_s_sleep(1);
          if ((unsigned int)(p0 >> 32) != tg)
            p0 = __hip_atomic_load(&pb[(wc + 0) * 16], __ATOMIC_RELAXED, __HIP_MEMORY_SCOPE_AGENT);
          if ((unsigned int)(p1 >> 32) != tg)
            p1 = __hip_atomic_load(&pb[(wc + 8) * 16], __ATOMIC_RELAXED, __HIP_MEMORY_SCOPE_AGENT);
          if ((unsigned int)(p2 >> 32) != tg)
            p2 = __hip_atomic_load(&pb[(wc + 16) * 16], __ATOMIC_RELAXED, __HIP_MEMORY_SCOPE_AGENT);
          if ((unsigned int)(p3 >> 32) != tg)
            p3 = __hip_atomic_load(&pb[(wc + 24) * 16], __ATOMIC_RELAXED, __HIP_MEMORY_SCOPE_AGENT);
          if (wc < 4 && (unsigned int)(p4 >> 32) != tg)
            p4 = __hip_atomic_load(&pb[(wc + 32) * 16], __ATOMIC_RELAXED, __HIP_MEMORY_SCOPE_AGENT);
        }
        ushort_t* bvw = bv + wr * 576;
#define VUPD(PV, CSV, VR, TC)                                                          \
        {                                                                              \
          float tot = (CSV) + __uint_as_float((unsigned int)(PV));                     \
          float vn = C_nu - EPS_OT * __logf(tot);                                      \
          VR = vn;                                                                     \
          bvw[(TC) * 16 + l] =                                                         \
              (ushort_t)f2bf(__expf(fminf(fmaxf(vn * INV_EPS, -80.f), 80.f)));         \
        }
        VUPD(p0, cs0, v_r0, wc + 0)
        VUPD(p1, cs1, v_r1, wc + 8)
        VUPD(p2, cs2, v_r2, wc + 16)
        VUPD(p3, cs3, v_r3, wc + 24)
        if (wc < 4) VUPD(p4, cs4, v_r4, wc + 32)
      }
    }
    bar_lds();
  }
  // ---- outputs straight from registers ----
  if (w < 8 && l < 16)
    gA[(size_t)s * 256 + rh * 128 + w * 16 + l] = u_r * INV_EPS;
  if (rh == 0 && w >= 8 && l < 16) {
    float* gBs = gB + (size_t)s * 576 + l;
    gBs[(wc + 0) * 16] = v_r0 * INV_EPS + 11.9012851f;   // +ln(147456)
    gBs[(wc + 8) * 16] = v_r1 * INV_EPS + 11.9012851f;
    gBs[(wc + 16) * 16] = v_r2 * INV_EPS + 11.9012851f;
    gBs[(wc + 24) * 16] = v_r3 * INV_EPS + 11.9012851f;
    if (wc < 4) gBs[(wc + 32) * 16] = v_r4 * INV_EPS + 11.9012851f;
  }
}

// ---------- scorev: out(bf16) = score @ V via MFMA (hi/lo P, bf16 V) ----------
__global__ __launch_bounds__(256) void scorev2_k(const ushort_t* __restrict__ E,
                                                 const ushort_t* __restrict__ vt,
                                                 const float* __restrict__ gA,
                                                 const float* __restrict__ gB,
                                                 ushort_t* __restrict__ Y) {
  __shared__ float gBs[576];
  const int s = blockIdx.x, i0 = blockIdx.y << 6;
  const int tid = threadIdx.x;
  const int w = tid >> 6, l = tid & 63, li = l & 15, lg = l >> 4;
  for (int j = tid; j < 576; j += 256) gBs[j] = gB[(size_t)s * 576 + j];
  const float ga = gA[(size_t)s * 256 + i0 + 16 * w + li];
  const ushort_t* Erow = E + (size_t)s * 147456 + (size_t)(i0 + 16 * w + li) * 576;
  f32x4 acc[4] = {};
  __syncthreads();
  for (int kst = 0; kst < 18; ++kst) {
    const int jb = kst * 32 + 8 * lg;
    Pk eu; eu.u = *(const uint4*)(Erow + jb);
    float pv[8];
#pragma unroll
    for (int jj = 0; jj < 8; ++jj) {
      unsigned int us = (unsigned int)(unsigned short)eu.s[jj];
      float e = bf2f(us);
      float le = __logf(e);
      pv[jj] = (1.0f + EPS_OT * le) * __expf(le + ga + gBs[jb + jj]);
    }
    Pk ph, pl;
#pragma unroll
    for (int jj = 0; jj < 8; ++jj) {
      unsigned int h = f2bf(pv[jj]);
      ((unsigned short*)&ph.s)[jj] = (unsigned short)h;
      ((unsigned short*)&pl.s)[jj] = (unsigned short)f2bf(pv[jj] - bf2f(h));
    }
#pragma unroll
    for (int nt = 0; nt < 4; ++nt) {
      Pk vf; vf.u = *(const uint4*)(vt + ((size_t)s * 64 + nt * 16 + li) * 576 + jb);
      acc[nt] = __builtin_amdgcn_mfma_f32_16x16x32_bf16(ph.s, vf.s, acc[nt], 0, 0, 0);
      acc[nt] = __builtin_amdgcn_mfma_f32_16x16x32_bf16(pl.s, vf.s, acc[nt], 0, 0, 0);
    }
  }
  const int b = s >> 3, h = s & 7;
#pragma unroll
  for (int nt = 0; nt < 4; ++nt)
#pragma unroll
    for (int reg = 0; reg < 4; ++reg)
      Y[((size_t)(b * 256 + i0 + 16 * w + 4 * lg + reg) << 9) + (h << 6) + nt * 16 + li] =
          (ushort_t)f2bf(acc[nt][reg]);
}

// ------------------------- final row l2norm (plain division) -------------------------
__global__ __launch_bounds__(256) void rownorm_k(const float* __restrict__ X,
                                                 float* __restrict__ out) {
  const size_t row = blockIdx.x;
  const int tid = threadIdx.x;
  float x0 = X[(row << 9) + tid], x1 = X[(row << 9) + 256 + tid];
  float st = fmaf(x0, x0, x1 * x1);
#pragma unroll
  for (int off = 32; off; off >>= 1) st += __shfl_xor(st, off, 64);
  __shared__ float ps[4];
  if ((tid & 63) == 0) ps[tid >> 6] = st;
  __syncthreads();
  const float inv = 1.0f / sqrtf(ps[0] + ps[1] + ps[2] + ps[3]);
  out[(row << 9) + tid] = x0 * inv;
  out[(row << 9) + 256 + tid] = x1 * inv;
}

extern "C" void kernel_launch(void* const* d_in, const int* in_sizes, int n_in,
                              void* d_out, int out_size, void* d_ws, size_t ws_size,
                              hipStream_t stream) {
  const float* F_t = (const float*)d_in[0];
  const float* F_s = (const float*)d_in[1];
  const float* Wq = (const float*)d_in[2];
  const float* bq = (const float*)d_in[3];
  const float* Wk = (const float*)d_in[4];
  const float* bk = (const float*)d_in[5];
  const float* Wv = (const float*)d_in[6];
  const float* bvb = (const float*)d_in[7];
  const float* Wp = (const float*)d_in[8];
  const float* bp = (const float*)d_in[9];
  float* out = (float*)d_out;

  ushort_t* u0 = (ushort_t*)d_ws;
  ushort_t* Fth = u0;                      //  2,097,152
  ushort_t* Ftl = Fth + 2097152;
  ushort_t* Fsh = Ftl + 2097152;           //  4,718,592
  ushort_t* Fsl = Fsh + 4718592;
  ushort_t* Wqh = Fsl + 4718592;           //  262,144 each
  ushort_t* Wql = Wqh + 262144;
  ushort_t* Wkh = Wql + 262144;
  ushort_t* Wkl = Wkh + 262144;
  ushort_t* Wvh = Wkl + 262144;
  ushort_t* Wvl = Wvh + 262144;
  ushort_t* Wph = Wvl + 262144;
  ushort_t* qh = Wph + 262144;             //  2,097,152
  ushort_t* ql = qh + 2097152;
  ushort_t* kh = ql + 2097152;             //  4,718,592
  ushort_t* kl = kh + 4718592;
  ushort_t* vt = kl + 4718592;             //  4,718,592  [128][64][576]
  ushort_t* Eb = vt + 4718592;             // 18,874,368  [128][256][576]
  ushort_t* T0b = Eb + 18874368;           //  2,097,152  (scorev out bf16)
  float* T1 = (float*)(T0b + 2097152);     //  2,097,152 f32
  float* gA = T1 + 2097152;                //  32,768
  float* gB = gA + 32768;                  //  73,728
  unsigned long long* gpart = (unsigned long long*)(gB + 73728);  // 256*1152 ull

  const float C_mu = (float)(0.05 * log(1.0 / 256.0 + 1e-8));
  const float C_nu = (float)(0.05 * log(1.0 / 576.0 + 1e-8));

  (void)hipFuncSetAttribute((const void*)sinkhorn16_k,
                            hipFuncAttributeMaxDynamicSharedMemorySize, SK_SMEM);

  pack_k<<<7680, 256, 0, stream>>>(F_t, F_s, Wq, Wk, Wv, Wp, Fth, Ftl, Fsh, Fsl,
                                   Wqh, Wql, Wkh, Wkl, Wvh, Wvl, Wph);
  gemmnorm2_k<<<dim3(64, 8), 256, 0, stream>>>(Fth, Ftl, Wqh, Wql, bq, qh, ql, 256);
  gemmnorm2_k<<<dim3(144, 8), 256, 0, stream>>>(Fsh, Fsl, Wkh, Wkl, bk, kh, kl, 576);
  gemmtrans2_k<<<dim3(144, 8), 256, 0, stream>>>(Fsh, Wvh, bvb, vt);
  simE2_k<<<dim3(128, 4, 9), 256, 0, stream>>>(qh, ql, kh, kl, Eb);
  sinkhorn16_k<<<256, 1024, SK_SMEM, stream>>>(Eb, gA, gB, gpart, C_mu, C_nu);
  scorev2_k<<<dim3(128, 4), 256, 0, stream>>>(Eb, vt, gA, gB, T0b);
  gemmplain_k<<<dim3(64, 8), 256, 0, stream>>>(T0b, Wph, bp, T1);
  rownorm_k<<<4096, 256, 0, stream>>>(T1, out);
}

// Round 9
// 359.308 us; speedup vs baseline: 1.2307x; 1.2307x over previous
//
#include <hip/hip_runtime.h>
#include <math.h>

#define EPS_OT 0.05f
#define INV_EPS 20.0f

typedef unsigned short ushort_t;
typedef __attribute__((ext_vector_type(8))) short short8;
typedef __attribute__((ext_vector_type(4))) float f32x4;
union Pk { uint4 u; short8 s; };

__device__ __forceinline__ unsigned int f2bf(float f) {  // RNE f32->bf16
  unsigned int u = __float_as_uint(f);
  return (u + 0x7FFFu + ((u >> 16) & 1u)) >> 16;
}
__device__ __forceinline__ float bf2f(unsigned int u) { return __uint_as_float(u << 16); }

// lgkmcnt-only barrier: orders LDS producer->consumer across the workgroup but
// does NOT drain vmcnt (mailbox store-ack / in-flight poll load survive it).
__device__ __forceinline__ void bar_lds() {
  asm volatile("s_waitcnt lgkmcnt(0)" ::: "memory");
  __builtin_amdgcn_s_barrier();
  asm volatile("" ::: "memory");
}

// ---------------- pack: fp32 -> hi/lo bf16 (one-time) ----------------
__global__ __launch_bounds__(256) void pack_k(const float* __restrict__ F_t,
                                              const float* __restrict__ F_s,
                                              const float* __restrict__ Wq,
                                              const float* __restrict__ Wk,
                                              const float* __restrict__ Wv,
                                              const float* __restrict__ Wp,
                                              ushort_t* __restrict__ Fth, ushort_t* __restrict__ Ftl,
                                              ushort_t* __restrict__ Fsh, ushort_t* __restrict__ Fsl,
                                              ushort_t* __restrict__ Wqh, ushort_t* __restrict__ Wql,
                                              ushort_t* __restrict__ Wkh, ushort_t* __restrict__ Wkl,
                                              ushort_t* __restrict__ Wvh, ushort_t* __restrict__ Wvl,
                                              ushort_t* __restrict__ Wph) {
  const int blk = blockIdx.x;
  const float* src; ushort_t* dh; ushort_t* dl; size_t off;
  if (blk < 2048)      { src = F_t; dh = Fth; dl = Ftl; off = (size_t)blk * 1024; }
  else if (blk < 6656) { src = F_s; dh = Fsh; dl = Fsl; off = (size_t)(blk - 2048) * 1024; }
  else if (blk < 6912) { src = Wq;  dh = Wqh; dl = Wql; off = (size_t)(blk - 6656) * 1024; }
  else if (blk < 7168) { src = Wk;  dh = Wkh; dl = Wkl; off = (size_t)(blk - 6912) * 1024; }
  else if (blk < 7424) { src = Wv;  dh = Wvh; dl = Wvl; off = (size_t)(blk - 7168) * 1024; }
  else                 { src = Wp;  dh = Wph; dl = nullptr; off = (size_t)(blk - 7424) * 1024; }
  const size_t i = off + (size_t)threadIdx.x * 4;
  float4 f = *(const float4*)(src + i);
  unsigned int h0 = f2bf(f.x), h1 = f2bf(f.y), h2 = f2bf(f.z), h3 = f2bf(f.w);
  uint2 hh; hh.x = h0 | (h1 << 16); hh.y = h2 | (h3 << 16);
  *(uint2*)(dh + i) = hh;
  if (dl) {
    uint2 ll;
    ll.x = f2bf(f.x - bf2f(h0)) | (f2bf(f.y - bf2f(h1)) << 16);
    ll.y = f2bf(f.z - bf2f(h2)) | (f2bf(f.w - bf2f(h3)) << 16);
    *(uint2*)(dl + i) = ll;
  }
}

// ====== hi/lo GEMM main loop on pre-packed bf16 (64x64 tile, K=512, 3-MFMA) ======
#define GEMM_HL_BODY()                                                                      \
  f32x4 acc[4] = {};                                                                        \
  for (int k0 = 0; k0 < 512; k0 += 64) {                                                    \
    uint4 a0 = *(const uint4*)(Xp_h + k0), a1 = *(const uint4*)(Xp_h + k0 + 8);             \
    uint4 b0 = *(const uint4*)(Xp_l + k0), b1 = *(const uint4*)(Xp_l + k0 + 8);             \
    uint4 c0 = *(const uint4*)(Wp_h + k0), c1 = *(const uint4*)(Wp_h + k0 + 8);             \
    uint4 d0 = *(const uint4*)(Wp_l + k0), d1 = *(const uint4*)(Wp_l + k0 + 8);             \
    __syncthreads();                                                                        \
    *(uint4*)&Xh[r][cg * 16] = a0; *(uint4*)&Xh[r][cg * 16 + 8] = a1;                       \
    *(uint4*)&Xl[r][cg * 16] = b0; *(uint4*)&Xl[r][cg * 16 + 8] = b1;                       \
    *(uint4*)&Wh[r][cg * 16] = c0; *(uint4*)&Wh[r][cg * 16 + 8] = c1;                       \
    *(uint4*)&Wl[r][cg * 16] = d0; *(uint4*)&Wl[r][cg * 16 + 8] = d1;                       \
    __syncthreads();                                                                        \
    _Pragma("unroll") for (int kst = 0; kst < 2; ++kst) {                                   \
      short8 ah = *(const short8*)&Xh[16 * w + li][kst * 32 + 8 * lg];                      \
      short8 al = *(const short8*)&Xl[16 * w + li][kst * 32 + 8 * lg];                      \
      _Pragma("unroll") for (int nt = 0; nt < 4; ++nt) {                                    \
        short8 bh = *(const short8*)&Wh[nt * 16 + li][kst * 32 + 8 * lg];                   \
        short8 bl = *(const short8*)&Wl[nt * 16 + li][kst * 32 + 8 * lg];                   \
        acc[nt] = __builtin_amdgcn_mfma_f32_16x16x32_bf16(ah, bh, acc[nt], 0, 0, 0);        \
        acc[nt] = __builtin_amdgcn_mfma_f32_16x16x32_bf16(ah, bl, acc[nt], 0, 0, 0);        \
        acc[nt] = __builtin_amdgcn_mfma_f32_16x16x32_bf16(al, bh, acc[nt], 0, 0, 0);        \
      }                                                                                     \
    }                                                                                       \
  }

// ====== plain bf16 GEMM main loop (64x64 tile, K=512, 1-MFMA) ======
#define GEMM_PL_BODY()                                                                      \
  f32x4 acc[4] = {};                                                                        \
  for (int k0 = 0; k0 < 512; k0 += 64) {                                                    \
    uint4 a0 = *(const uint4*)(Xp_h + k0), a1 = *(const uint4*)(Xp_h + k0 + 8);             \
    uint4 c0 = *(const uint4*)(Wp_h + k0), c1 = *(const uint4*)(Wp_h + k0 + 8);             \
    __syncthreads();                                                                        \
    *(uint4*)&Xh[r][cg * 16] = a0; *(uint4*)&Xh[r][cg * 16 + 8] = a1;                       \
    *(uint4*)&Wh[r][cg * 16] = c0; *(uint4*)&Wh[r][cg * 16 + 8] = c1;                       \
    __syncthreads();                                                                        \
    _Pragma("unroll") for (int kst = 0; kst < 2; ++kst) {                                   \
      short8 ah = *(const short8*)&Xh[16 * w + li][kst * 32 + 8 * lg];                      \
      _Pragma("unroll") for (int nt = 0; nt < 4; ++nt) {                                    \
        short8 bh = *(const short8*)&Wh[nt * 16 + li][kst * 32 + 8 * lg];                   \
        acc[nt] = __builtin_amdgcn_mfma_f32_16x16x32_bf16(ah, bh, acc[nt], 0, 0, 0);        \
      }                                                                                     \
    }                                                                                       \
  }

// ------- fused GEMM + per-head l2norm -> hi/lo bf16 [B*H][Nn][64] (q and k) -------
__global__ __launch_bounds__(256) void gemmnorm2_k(const ushort_t* __restrict__ Xg_h,
                                                   const ushort_t* __restrict__ Xg_l,
                                                   const ushort_t* __restrict__ Wg_h,
                                                   const ushort_t* __restrict__ Wg_l,
                                                   const float* __restrict__ bias,
                                                   ushort_t* __restrict__ oh,
                                                   ushort_t* __restrict__ ol, int Nn) {
  __shared__ ushort_t Xh[64][72], Xl[64][72], Wh[64][72], Wl[64][72];
  const int tid = threadIdx.x;
  const int w = tid >> 6, l = tid & 63, li = l & 15, lg = l >> 4;
  const int r = tid >> 2, cg = tid & 3;
  const int m0 = blockIdx.x << 6;
  const int h = blockIdx.y, n0 = h << 6;
  const ushort_t* Xp_h = Xg_h + (size_t)(m0 + r) * 512 + cg * 16;
  const ushort_t* Xp_l = Xg_l + (size_t)(m0 + r) * 512 + cg * 16;
  const ushort_t* Wp_h = Wg_h + (size_t)(n0 + r) * 512 + cg * 16;
  const ushort_t* Wp_l = Wg_l + (size_t)(n0 + r) * 512 + cg * 16;
  GEMM_HL_BODY()
  float v[4][4];
  float ss[4] = {0.f, 0.f, 0.f, 0.f};
#pragma unroll
  for (int nt = 0; nt < 4; ++nt) {
    float bb = bias[n0 + nt * 16 + li];
#pragma unroll
    for (int reg = 0; reg < 4; ++reg) {
      float y = acc[nt][reg] + bb;
      v[nt][reg] = y;
      ss[reg] = fmaf(y, y, ss[reg]);
    }
  }
#pragma unroll
  for (int off = 1; off < 16; off <<= 1)
#pragma unroll
    for (int reg = 0; reg < 4; ++reg) ss[reg] += __shfl_xor(ss[reg], off, 64);
  const int b = m0 / Nn;
  const int nbase = m0 - b * Nn;
  const size_t base = ((size_t)(b * 8 + h) * Nn + nbase + 16 * w + 4 * lg) * 64;
#pragma unroll
  for (int reg = 0; reg < 4; ++reg) {
    float inv = 1.0f / fmaxf(sqrtf(ss[reg]), 1e-12f);
#pragma unroll
    for (int nt = 0; nt < 4; ++nt) {
      float y = v[nt][reg] * inv;
      unsigned int hi = f2bf(y);
      size_t idx = base + (size_t)reg * 64 + nt * 16 + li;
      oh[idx] = (ushort_t)hi;
      ol[idx] = (ushort_t)f2bf(y - bf2f(hi));
    }
  }
}

// ------- fused plain-bf16 GEMM + transpose: vt[s][c 0..63][j 0..575] (v path) -------
__global__ __launch_bounds__(256) void gemmtrans2_k(const ushort_t* __restrict__ Xg_h,
                                                    const ushort_t* __restrict__ Wg_h,
                                                    const float* __restrict__ bias,
                                                    ushort_t* __restrict__ vt) {
  __shared__ ushort_t Xh[64][72], Wh[64][72];
  __shared__ ushort_t Vs[64 * 73];
  const int tid = threadIdx.x;
  const int w = tid >> 6, l = tid & 63, li = l & 15, lg = l >> 4;
  const int r = tid >> 2, cg = tid & 3;
  const int m0 = blockIdx.x << 6;
  const int h = blockIdx.y, n0 = h << 6;
  const ushort_t* Xp_h = Xg_h + (size_t)(m0 + r) * 512 + cg * 16;
  const ushort_t* Wp_h = Wg_h + (size_t)(n0 + r) * 512 + cg * 16;
  GEMM_PL_BODY()
#pragma unroll
  for (int nt = 0; nt < 4; ++nt) {
    float bb = bias[n0 + nt * 16 + li];
#pragma unroll
    for (int reg = 0; reg < 4; ++reg)
      Vs[(16 * w + 4 * lg + reg) * 73 + nt * 16 + li] = (ushort_t)f2bf(acc[nt][reg] + bb);
  }
  __syncthreads();
  const int a9 = m0 >> 6;
  const int b = a9 / 9;
  const int nbase = m0 - b * 576;
  const int s = b * 8 + h;
  const int c = tid >> 2, q4 = tid & 3;
  ushort_t tmp[16];
#pragma unroll
  for (int jj = 0; jj < 16; ++jj) tmp[jj] = Vs[(q4 * 16 + jj) * 73 + c];
  ushort_t* op = vt + ((size_t)s * 64 + c) * 576 + nbase + q4 * 16;
  *(uint4*)op = *(uint4*)&tmp[0];
  *(uint4*)(op + 8) = *(uint4*)&tmp[8];
}

// ------- final plain-bf16 GEMM (scorev-out bf16 @ Wp_h) -> fp32 -------
__global__ __launch_bounds__(256) void gemmplain_k(const ushort_t* __restrict__ Xg_h,
                                                   const ushort_t* __restrict__ Wg_h,
                                                   const float* __restrict__ bias,
                                                   float* __restrict__ Y) {
  __shared__ ushort_t Xh[64][72], Wh[64][72];
  const int tid = threadIdx.x;
  const int w = tid >> 6, l = tid & 63, li = l & 15, lg = l >> 4;
  const int r = tid >> 2, cg = tid & 3;
  const int m0 = blockIdx.x << 6, n0 = blockIdx.y << 6;
  const ushort_t* Xp_h = Xg_h + (size_t)(m0 + r) * 512 + cg * 16;
  const ushort_t* Wp_h = Wg_h + (size_t)(n0 + r) * 512 + cg * 16;
  GEMM_PL_BODY()
#pragma unroll
  for (int nt = 0; nt < 4; ++nt) {
    float bb = bias[n0 + nt * 16 + li];
#pragma unroll
    for (int reg = 0; reg < 4; ++reg)
      Y[(size_t)(m0 + 16 * w + 4 * lg + reg) * 512 + n0 + nt * 16 + li] = acc[nt][reg] + bb;
  }
}

// -------- Sinkhorn v17: exact v15 loop + fused E-computation prologue --------
// Prologue replaces the 37.7MB E load: each block computes its own [128][576]
// E half-slab from q/k (16 waves x 18 tiles x 6 MFMAs, bit-identical to the
// old simE2_k: same MFMA order, same __expf, same f2bf, same layout), writes
// Elds for the loop's frag build AND bulk-copies it to global E for scorev2.
// simE2_k dispatch deleted. Loop/mailbox/epilogue are byte-identical to v15.
#define SK_SMEM 147456

__global__ __launch_bounds__(1024, 1) void sinkhorn17_k(const ushort_t* __restrict__ qh,
                                                        const ushort_t* __restrict__ ql,
                                                        const ushort_t* __restrict__ kh,
                                                        const ushort_t* __restrict__ kl,
                                                        ushort_t* __restrict__ Eo,
                                                        float* __restrict__ gA,
                                                        float* __restrict__ gB,
                                                        unsigned long long* __restrict__ gpart,
                                                        float C_mu, float C_nu) {
  extern __shared__ char smem[];
  const int g = blockIdx.x, s = g >> 1, rh = g & 1, pg = g ^ 1;
  const int tid = threadIdx.x, w = tid >> 6, l = tid & 63, li = l & 15, lg = l >> 4;
  unsigned long long* myP = gpart + (size_t)g * 1152;
  const unsigned long long* prP = gpart + (size_t)pg * 1152;

  ushort_t* Elds = (ushort_t*)smem;  // [128][576]
  // ---- prologue: compute E half-slab (rows rh*128..+128 of slab s) ----
  {
    const int rt = w & 7;                       // row-tile within half-slab
    const int qrow = rh * 128 + rt * 16 + li;   // row within s-slab
    const size_t qoff = ((size_t)s * 256 + qrow) * 64 + 8 * lg;
    short8 aH0 = *(const short8*)(qh + qoff), aH1 = *(const short8*)(qh + qoff + 32);
    short8 aL0 = *(const short8*)(ql + qoff), aL1 = *(const short8*)(ql + qoff + 32);
    const int c0 = (w >> 3) * 18;               // col-tile half
    for (int ci = 0; ci < 18; ++ci) {
      const int ct = c0 + ci;
      const size_t koff = ((size_t)s * 576 + ct * 16 + li) * 64 + 8 * lg;
      short8 bH0 = *(const short8*)(kh + koff), bH1 = *(const short8*)(kh + koff + 32);
      short8 bL0 = *(const short8*)(kl + koff), bL1 = *(const short8*)(kl + koff + 32);
      f32x4 acc = {0.f, 0.f, 0.f, 0.f};
      acc = __builtin_amdgcn_mfma_f32_16x16x32_bf16(aH0, bH0, acc, 0, 0, 0);
      acc = __builtin_amdgcn_mfma_f32_16x16x32_bf16(aH1, bH1, acc, 0, 0, 0);
      acc = __builtin_amdgcn_mfma_f32_16x16x32_bf16(aH0, bL0, acc, 0, 0, 0);
      acc = __builtin_amdgcn_mfma_f32_16x16x32_bf16(aH1, bL1, acc, 0, 0, 0);
      acc = __builtin_amdgcn_mfma_f32_16x16x32_bf16(aL0, bH0, acc, 0, 0, 0);
      acc = __builtin_amdgcn_mfma_f32_16x16x32_bf16(aL1, bH1, acc, 0, 0, 0);
#pragma unroll
      for (int reg = 0; reg < 4; ++reg) {
        float e = __expf((acc[reg] - 1.0f) * INV_EPS);
        Elds[(rt * 16 + 4 * lg + reg) * 576 + ct * 16 + li] = (ushort_t)f2bf(e);
      }
    }
  }
  __syncthreads();
  // ---- bulk-copy Elds -> global E (for scorev2), coalesced; overlaps frag build ----
  {
    uint4* Eg4 = (uint4*)(Eo + (size_t)s * 147456 + (size_t)rh * 73728);
    const uint4* El4 = (const uint4*)Elds;
    for (int idx = tid; idx < 9216; idx += 1024) Eg4[idx] = El4[idx];
  }

  // mv1 frags (A-layout): wave w owns row-tile (w&7), k-chunks (w>>3)*9 + c
  const int art = (w & 7) * 16 + li;
  const int akb = (w >> 3) * 9;
  short8 afr[9];
#pragma unroll
  for (int c = 0; c < 9; ++c)
    afr[c] = *(const short8*)(Elds + art * 576 + (akb + c) * 32 + 8 * lg);

  // mv2 frags (B-layout): wave w owns col-tiles {w, w+16} (+{w+32} if w<4)
  short8 bfr0, bfr1, bfr2, bfr3, bfr4, bfr5, bfr6, bfr7, bfr8, bfr9, bfr10, bfr11;
#define BFR_BUILD(dst, tc, q)                                                  \
  {                                                                            \
    const ushort_t* p = Elds + ((q) * 32 + 8 * lg) * 576 + (tc) * 16 + li;     \
    Pk pk;                                                                     \
    pk.u.x = (unsigned int)p[0]    | ((unsigned int)p[576]  << 16);            \
    pk.u.y = (unsigned int)p[1152] | ((unsigned int)p[1728] << 16);            \
    pk.u.z = (unsigned int)p[2304] | ((unsigned int)p[2880] << 16);            \
    pk.u.w = (unsigned int)p[3456] | ((unsigned int)p[4032] << 16);            \
    dst = pk.s;                                                                \
  }
  BFR_BUILD(bfr0, w, 0) BFR_BUILD(bfr1, w, 1) BFR_BUILD(bfr2, w, 2) BFR_BUILD(bfr3, w, 3)
  BFR_BUILD(bfr4, w + 16, 0) BFR_BUILD(bfr5, w + 16, 1)
  BFR_BUILD(bfr6, w + 16, 2) BFR_BUILD(bfr7, w + 16, 3)
  if (w < 4) {
    BFR_BUILD(bfr8, w + 32, 0) BFR_BUILD(bfr9, w + 32, 1)
    BFR_BUILD(bfr10, w + 32, 2) BFR_BUILD(bfr11, w + 32, 3)
  } else {
    bfr8 = bfr0; bfr9 = bfr1; bfr10 = bfr2; bfr11 = bfr3;  // unused for w>=4
  }
  __syncthreads();

  // ---- overlay scratch (Elds consumed; E lives in registers) ----
  float* uu = (float*)smem;             // 128
  float* vv = uu + 128;                 // 576
  ushort_t* au = (ushort_t*)(vv + 576); // 128 bf16
  ushort_t* bv = au + 128;              // 576 bf16 (pad to 768 ush total)
  float* rpart = (float*)(au + 768);    // [2][128]
  float* cso = rpart + 256;             // 576

  if (tid < 128) { uu[tid] = 0.0f; au[tid] = (ushort_t)0x3F80; }
  if (tid < 576) { vv[tid] = 0.0f; bv[tid] = (ushort_t)0x3F80; }
  __syncthreads();

  const int jj = tid - 128;
  const bool poller = (tid >= 128) && (tid < 704);

  for (int t = 0; t < 100; ++t) {
    const int par = t & 1;
    // ---- merged phase AB: mv2 (2+2 split chains, publish ASAP) then mv1 (3x3) ----
    {
      Pk q0, q1, q2, q3;
      q0.u = *(const uint4*)(au + 8 * lg);
      q1.u = *(const uint4*)(au + 32 + 8 * lg);
      q2.u = *(const uint4*)(au + 64 + 8 * lg);
      q3.u = *(const uint4*)(au + 96 + 8 * lg);
#define MV2_TILE(tc, f0, f1, f2, f3)                                                  \
      {                                                                               \
        f32x4 a2 = {0.f, 0.f, 0.f, 0.f}, b2 = {0.f, 0.f, 0.f, 0.f};                   \
        a2 = __builtin_amdgcn_mfma_f32_16x16x32_bf16(q0.s, f0, a2, 0, 0, 0);          \
        b2 = __builtin_amdgcn_mfma_f32_16x16x32_bf16(q2.s, f2, b2, 0, 0, 0);          \
        a2 = __builtin_amdgcn_mfma_f32_16x16x32_bf16(q1.s, f1, a2, 0, 0, 0);          \
        b2 = __builtin_amdgcn_mfma_f32_16x16x32_bf16(q3.s, f3, b2, 0, 0, 0);          \
        if (l < 16) {                                                                 \
          const int col = (tc) * 16 + l;                                              \
          float cs = a2[0] + b2[0];                                                   \
          cso[col] = cs;                                                              \
          unsigned long long pv = (unsigned long long)__float_as_uint(cs) |           \
                                  ((unsigned long long)(unsigned int)(t + 1) << 32);  \
          __hip_atomic_store(&myP[par * 576 + col], pv, __ATOMIC_RELAXED,             \
                             __HIP_MEMORY_SCOPE_AGENT);                               \
        }                                                                             \
      }
      MV2_TILE(w, bfr0, bfr1, bfr2, bfr3)
      MV2_TILE(w + 16, bfr4, bfr5, bfr6, bfr7)
      if (w < 4) MV2_TILE(w + 32, bfr8, bfr9, bfr10, bfr11)
    }
    {
      f32x4 x1 = {0.f, 0.f, 0.f, 0.f}, y1 = {0.f, 0.f, 0.f, 0.f}, z1 = {0.f, 0.f, 0.f, 0.f};
      Pk b0, b1, b2, b3, b4, b5, b6, b7, b8;
      b0.u = *(const uint4*)(bv + (akb + 0) * 32 + 8 * lg);
      b1.u = *(const uint4*)(bv + (akb + 1) * 32 + 8 * lg);
      b2.u = *(const uint4*)(bv + (akb + 2) * 32 + 8 * lg);
      b3.u = *(const uint4*)(bv + (akb + 3) * 32 + 8 * lg);
      b4.u = *(const uint4*)(bv + (akb + 4) * 32 + 8 * lg);
      b5.u = *(const uint4*)(bv + (akb + 5) * 32 + 8 * lg);
      b6.u = *(const uint4*)(bv + (akb + 6) * 32 + 8 * lg);
      b7.u = *(const uint4*)(bv + (akb + 7) * 32 + 8 * lg);
      b8.u = *(const uint4*)(bv + (akb + 8) * 32 + 8 * lg);
      x1 = __builtin_amdgcn_mfma_f32_16x16x32_bf16(b0.s, afr[0], x1, 0, 0, 0);
      y1 = __builtin_amdgcn_mfma_f32_16x16x32_bf16(b3.s, afr[3], y1, 0, 0, 0);
      z1 = __builtin_amdgcn_mfma_f32_16x16x32_bf16(b6.s, afr[6], z1, 0, 0, 0);
      x1 = __builtin_amdgcn_mfma_f32_16x16x32_bf16(b1.s, afr[1], x1, 0, 0, 0);
      y1 = __builtin_amdgcn_mfma_f32_16x16x32_bf16(b4.s, afr[4], y1, 0, 0, 0);
      z1 = __builtin_amdgcn_mfma_f32_16x16x32_bf16(b7.s, afr[7], z1, 0, 0, 0);
      x1 = __builtin_amdgcn_mfma_f32_16x16x32_bf16(b2.s, afr[2], x1, 0, 0, 0);
      y1 = __builtin_amdgcn_mfma_f32_16x16x32_bf16(b5.s, afr[5], y1, 0, 0, 0);
      z1 = __builtin_amdgcn_mfma_f32_16x16x32_bf16(b8.s, afr[8], z1, 0, 0, 0);
      if (l < 16) rpart[(w >> 3) * 128 + (w & 7) * 16 + l] = (x1[0] + y1[0]) + z1[0];
    }
    // ---- late-issued poll prefetch ----
    __builtin_amdgcn_sched_barrier(0);
    unsigned long long p0 = 0;
    if (poller)
      p0 = __hip_atomic_load(&prP[par * 576 + jj], __ATOMIC_RELAXED, __HIP_MEMORY_SCOPE_AGENT);
    bar_lds();
    // ---- phase C: u-update (tid<128) || tag-check prefetched + v-update ----
    if (tid < 128) {
      float rs = rpart[tid] + rpart[128 + tid];
      float un = C_mu - EPS_OT * __logf(rs);
      uu[tid] = un;
      au[tid] = (ushort_t)f2bf(__expf(fminf(fmaxf(un * INV_EPS, -80.f), 80.f)));
    } else if (tid < 704) {
      const unsigned int tg = (unsigned int)(t + 1);
      while ((unsigned int)(p0 >> 32) != tg) {
        __builtin_amdgcn_s_sleep(1);
        p0 = __hip_atomic_load(&prP[par * 576 + jj], __ATOMIC_RELAXED, __HIP_MEMORY_SCOPE_AGENT);
      }
      float tot = cso[jj] + __uint_as_float((unsigned int)p0);
      float vn = C_nu - EPS_OT * __logf(tot);
      vv[jj] = vn;
      bv[jj] = (ushort_t)f2bf(__expf(fminf(fmaxf(vn * INV_EPS, -80.f), 80.f)));
    }
    bar_lds();
  }
  // ---- epilogue: v_100 (only rh==0 needs it for gB) ----
  if (rh == 0 && tid >= 128 && tid < 704) {
    unsigned long long p0;
    for (;;) {
      p0 = __hip_atomic_load(&prP[576 + jj], __ATOMIC_RELAXED, __HIP_MEMORY_SCOPE_AGENT);
      if ((unsigned int)(p0 >> 32) == 100u) break;
      __builtin_amdgcn_s_sleep(1);
    }
    float tot = cso[jj] + __uint_as_float((unsigned int)p0);
    vv[jj] = C_nu - EPS_OT * __logf(tot);
  }
  __syncthreads();
  if (tid < 128) gA[(size_t)s * 256 + rh * 128 + tid] = uu[tid] * INV_EPS;
  if (rh == 0 && tid < 576) gB[(size_t)s * 576 + tid] = vv[tid] * INV_EPS + 11.9012851f;  // +ln(147456)
}

// ---------- scorev: out(bf16) = score @ V via MFMA (hi/lo P, bf16 V) ----------
__global__ __launch_bounds__(256) void scorev2_k(const ushort_t* __restrict__ E,
                                                 const ushort_t* __restrict__ vt,
                                                 const float* __restrict__ gA,
                                                 const float* __restrict__ gB,
                                                 ushort_t* __restrict__ Y) {
  __shared__ float gBs[576];
  const int s = blockIdx.x, i0 = blockIdx.y << 6;
  const int tid = threadIdx.x;
  const int w = tid >> 6, l = tid & 63, li = l & 15, lg = l >> 4;
  for (int j = tid; j < 576; j += 256) gBs[j] = gB[(size_t)s * 576 + j];
  const float ga = gA[(size_t)s * 256 + i0 + 16 * w + li];
  const ushort_t* Erow = E + (size_t)s * 147456 + (size_t)(i0 + 16 * w + li) * 576;
  f32x4 acc[4] = {};
  __syncthreads();
  for (int kst = 0; kst < 18; ++kst) {
    const int jb = kst * 32 + 8 * lg;
    Pk eu; eu.u = *(const uint4*)(Erow + jb);
    float pv[8];
#pragma unroll
    for (int jj = 0; jj < 8; ++jj) {
      unsigned int us = (unsigned int)(unsigned short)eu.s[jj];
      float e = bf2f(us);
      float le = __logf(e);
      pv[jj] = (1.0f + EPS_OT * le) * __expf(le + ga + gBs[jb + jj]);
    }
    Pk ph, pl;
#pragma unroll
    for (int jj = 0; jj < 8; ++jj) {
      unsigned int h = f2bf(pv[jj]);
      ((unsigned short*)&ph.s)[jj] = (unsigned short)h;
      ((unsigned short*)&pl.s)[jj] = (unsigned short)f2bf(pv[jj] - bf2f(h));
    }
#pragma unroll
    for (int nt = 0; nt < 4; ++nt) {
      Pk vf; vf.u = *(const uint4*)(vt + ((size_t)s * 64 + nt * 16 + li) * 576 + jb);
      acc[nt] = __builtin_amdgcn_mfma_f32_16x16x32_bf16(ph.s, vf.s, acc[nt], 0, 0, 0);
      acc[nt] = __builtin_amdgcn_mfma_f32_16x16x32_bf16(pl.s, vf.s, acc[nt], 0, 0, 0);
    }
  }
  const int b = s >> 3, h = s & 7;
#pragma unroll
  for (int nt = 0; nt < 4; ++nt)
#pragma unroll
    for (int reg = 0; reg < 4; ++reg)
      Y[((size_t)(b * 256 + i0 + 16 * w + 4 * lg + reg) << 9) + (h << 6) + nt * 16 + li] =
          (ushort_t)f2bf(acc[nt][reg]);
}

// ------------------------- final row l2norm (plain division) -------------------------
__global__ __launch_bounds__(256) void rownorm_k(const float* __restrict__ X,
                                                 float* __restrict__ out) {
  const size_t row = blockIdx.x;
  const int tid = threadIdx.x;
  float x0 = X[(row << 9) + tid], x1 = X[(row << 9) + 256 + tid];
  float st = fmaf(x0, x0, x1 * x1);
#pragma unroll
  for (int off = 32; off; off >>= 1) st += __shfl_xor(st, off, 64);
  __shared__ float ps[4];
  if ((tid & 63) == 0) ps[tid >> 6] = st;
  __syncthreads();
  const float inv = 1.0f / sqrtf(ps[0] + ps[1] + ps[2] + ps[3]);
  out[(row << 9) + tid] = x0 * inv;
  out[(row << 9) + 256 + tid] = x1 * inv;
}

extern "C" void kernel_launch(void* const* d_in, const int* in_sizes, int n_in,
                              void* d_out, int out_size, void* d_ws, size_t ws_size,
                              hipStream_t stream) {
  const float* F_t = (const float*)d_in[0];
  const float* F_s = (const float*)d_in[1];
  const float* Wq = (const float*)d_in[2];
  const float* bq = (const float*)d_in[3];
  const float* Wk = (const float*)d_in[4];
  const float* bk = (const float*)d_in[5];
  const float* Wv = (const float*)d_in[6];
  const float* bvb = (const float*)d_in[7];
  const float* Wp = (const float*)d_in[8];
  const float* bp = (const float*)d_in[9];
  float* out = (float*)d_out;

  ushort_t* u0 = (ushort_t*)d_ws;
  ushort_t* Fth = u0;                      //  2,097,152
  ushort_t* Ftl = Fth + 2097152;
  ushort_t* Fsh = Ftl + 2097152;           //  4,718,592
  ushort_t* Fsl = Fsh + 4718592;
  ushort_t* Wqh = Fsl + 4718592;           //  262,144 each
  ushort_t* Wql = Wqh + 262144;
  ushort_t* Wkh = Wql + 262144;
  ushort_t* Wkl = Wkh + 262144;
  ushort_t* Wvh = Wkl + 262144;
  ushort_t* Wvl = Wvh + 262144;
  ushort_t* Wph = Wvl + 262144;
  ushort_t* qh = Wph + 262144;             //  2,097,152
  ushort_t* ql = qh + 2097152;
  ushort_t* kh = ql + 2097152;             //  4,718,592
  ushort_t* kl = kh + 4718592;
  ushort_t* vt = kl + 4718592;             //  4,718,592  [128][64][576]
  ushort_t* Eb = vt + 4718592;             // 18,874,368  [128][256][576]
  ushort_t* T0b = Eb + 18874368;           //  2,097,152  (scorev out bf16)
  float* T1 = (float*)(T0b + 2097152);     //  2,097,152 f32
  float* gA = T1 + 2097152;                //  32,768
  float* gB = gA + 32768;                  //  73,728
  unsigned long long* gpart = (unsigned long long*)(gB + 73728);  // 256*1152 ull

  const float C_mu = (float)(0.05 * log(1.0 / 256.0 + 1e-8));
  const float C_nu = (float)(0.05 * log(1.0 / 576.0 + 1e-8));

  (void)hipFuncSetAttribute((const void*)sinkhorn17_k,
                            hipFuncAttributeMaxDynamicSharedMemorySize, SK_SMEM);

  pack_k<<<7680, 256, 0, stream>>>(F_t, F_s, Wq, Wk, Wv, Wp, Fth, Ftl, Fsh, Fsl,
                                   Wqh, Wql, Wkh, Wkl, Wvh, Wvl, Wph);
  gemmnorm2_k<<<dim3(64, 8), 256, 0, stream>>>(Fth, Ftl, Wqh, Wql, bq, qh, ql, 256);
  gemmnorm2_k<<<dim3(144, 8), 256, 0, stream>>>(Fsh, Fsl, Wkh, Wkl, bk, kh, kl, 576);
  gemmtrans2_k<<<dim3(144, 8), 256, 0, stream>>>(Fsh, Wvh, bvb, vt);
  sinkhorn17_k<<<256, 1024, SK_SMEM, stream>>>(qh, ql, kh, kl, Eb, gA, gB, gpart, C_mu, C_nu);
  scorev2_k<<<dim3(128, 4), 256, 0, stream>>>(Eb, vt, gA, gB, T0b);
  gemmplain_k<<<dim3(64, 8), 256, 0, stream>>>(T0b, Wph, bp, T1);
  rownorm_k<<<4096, 256, 0, stream>>>(T1, out);
}